// Round 4
// baseline (1097.780 us; speedup 1.0000x reference)
//
#include <hip/hip_runtime.h>

#define T 3
#define E 500000
#define F 128
#define H 64
#define B 1024

// ---- helpers ----------------------------------------------------------

__device__ __forceinline__ float tanh_fast(float x) {
  // tanh(x) = 1 - 2/(exp(2x)+1); robust at +-inf
  float e = __expf(2.0f * x);
  return 1.0f - 2.0f / (e + 1.0f);
}

// ---- kernel 0: init ----------------------------------------------------

__global__ void k_init(unsigned* __restrict__ cnt, float* __restrict__ ssum) {
  int idx = blockIdx.x * blockDim.x + threadIdx.x;
  if (idx < T * B) {
    cnt[idx] = 0u;
    ssum[idx] = 0.0f;
  }
}

// ---- kernel 1: per-edge MLP -> ex = exp(score); segment sum + hist ----
// Block = 64 edges x 4 h-chunks (one chunk per wave). Each thread keeps
// only acc[16] (register-resident; round 2/3 showed the allocator spills
// any >=64-float per-thread array). chunk is wave-uniform via
// readfirstlane -> all weight loads are scalar (s_load + v_fmac(v,s)).
// No max-subtraction: |score| <= ||W2||_1 ~ 6, exp() cannot overflow.

__global__ __launch_bounds__(256, 4) void k_score(
    const float* __restrict__ ea, const int* __restrict__ batch,
    const float* __restrict__ W1, const float* __restrict__ b1,
    const float* __restrict__ W2, const float* __restrict__ b2,
    float* __restrict__ exarr, float* __restrict__ ssum,
    unsigned* __restrict__ cnt) {
  int t = blockIdx.y;
  int lane = threadIdx.x & 63;
  int chunk = __builtin_amdgcn_readfirstlane(threadIdx.x >> 6);  // 0..3
  int e = blockIdx.x * 64 + lane;
  int ec = e < E ? e : E - 1;  // clamp loads; stores predicated

  const float4* row = (const float4*)(ea + ((size_t)t * E + ec) * (size_t)F);
  const float* w1 = W1 + (size_t)t * F * H + chunk * 16;  // [F][H] row-major

  float acc[16];
#pragma unroll
  for (int j = 0; j < 16; ++j) acc[j] = 0.0f;

#pragma unroll 2
  for (int i = 0; i < F / 4; ++i) {
    float4 rv = row[i];
    const float* w = w1 + (4 * i) * H;  // scalar address (t,chunk,i uniform)
#pragma unroll
    for (int j = 0; j < 16; ++j) acc[j] = fmaf(rv.x, w[j], acc[j]);
#pragma unroll
    for (int j = 0; j < 16; ++j) acc[j] = fmaf(rv.y, w[H + j], acc[j]);
#pragma unroll
    for (int j = 0; j < 16; ++j) acc[j] = fmaf(rv.z, w[2 * H + j], acc[j]);
#pragma unroll
    for (int j = 0; j < 16; ++j) acc[j] = fmaf(rv.w, w[3 * H + j], acc[j]);
  }

  const float* b1t = b1 + t * H + chunk * 16;
  const float* w2t = W2 + t * H + chunk * 16;
  float psc = 0.0f;
#pragma unroll
  for (int j = 0; j < 16; ++j) {
    float h = tanh_fast(acc[j] + b1t[j]);
    psc = fmaf(h, w2t[j], psc);
  }

  __shared__ float part[4][64];
  part[chunk][lane] = psc;
  __syncthreads();
  if (chunk == 0 && e < E) {
    float sc = ((part[0][lane] + part[1][lane]) +
                (part[2][lane] + part[3][lane])) + b2[t];
    float ex = __expf(sc);
    int b = batch[(size_t)t * E + e];
    exarr[(size_t)t * E + e] = ex;
    atomicAdd(&ssum[t * B + b], ex);
    atomicAdd(&cnt[t * B + b], 1u);
  }
}

// ---- kernel 2: prefix sums (edge-list offsets) ------------------------

__global__ void k_scan(const unsigned* __restrict__ cnt,
                       unsigned* __restrict__ offs,
                       unsigned* __restrict__ cursor) {
  __shared__ unsigned s[B];
  int tid = threadIdx.x;
  for (int t = 0; t < T; ++t) {
    unsigned v = cnt[t * B + tid];
    s[tid] = v;
    __syncthreads();
    for (int d = 1; d < B; d <<= 1) {
      unsigned x = (tid >= d) ? s[tid - d] : 0u;
      __syncthreads();
      s[tid] += x;
      __syncthreads();
    }
    unsigned excl = s[tid] - v;   // exclusive scan
    offs[t * B + tid] = excl;
    cursor[t * B + tid] = excl;
    __syncthreads();
  }
}

// ---- kernel 3: counting-sort scatter of edge ids ----------------------

__global__ __launch_bounds__(256) void k_scatter(
    const int* __restrict__ batch, unsigned* __restrict__ cursor,
    unsigned* __restrict__ eid) {
  int t = blockIdx.y;
  int e = blockIdx.x * 256 + threadIdx.x;
  if (e >= E) return;
  int b = batch[t * E + e];
  unsigned pos = atomicAdd(&cursor[t * B + b], 1u);
  eid[(size_t)t * E + pos] = e;
}

// ---- kernel 4: per-graph weighted gather-sum (float4) -----------------

__global__ __launch_bounds__(512) void k_pool(
    const float* __restrict__ ea, const float* __restrict__ exarr,
    const float* __restrict__ ssum, const unsigned* __restrict__ offs,
    const unsigned* __restrict__ cnt, const unsigned* __restrict__ eid,
    float* __restrict__ out) {
  int b = blockIdx.x;
  int f4 = threadIdx.x & 31;   // float4 index within row (32 x 16B = 512B)
  int g = threadIdx.x >> 5;    // 16 edge groups

  float4 total = {0.f, 0.f, 0.f, 0.f};
  for (int t = 0; t < T; ++t) {
    unsigned c = cnt[t * B + b];
    if (c == 0u) continue;
    unsigned o = offs[t * B + b];
    const unsigned* ids = eid + (size_t)t * E + o;
    const float* exs = exarr + (size_t)t * E;
    const float4* eat = (const float4*)(ea + (size_t)t * E * (size_t)F);
    float4 part = {0.f, 0.f, 0.f, 0.f};
#pragma unroll 4
    for (unsigned i = g; i < c; i += 16) {
      unsigned id = ids[i];                 // shared across 32-lane group
      float w = exs[id];
      float4 v = eat[(size_t)id * 32 + f4]; // 32 lanes x 16B = full row
      part.x = fmaf(w, v.x, part.x);
      part.y = fmaf(w, v.y, part.y);
      part.z = fmaf(w, v.z, part.z);
      part.w = fmaf(w, v.w, part.w);
    }
    float scale = (1.0f / 3.0f) / ssum[t * B + b];
    total.x = fmaf(part.x, scale, total.x);
    total.y = fmaf(part.y, scale, total.y);
    total.z = fmaf(part.z, scale, total.z);
    total.w = fmaf(part.w, scale, total.w);
  }

  __shared__ float4 red[512];
  red[threadIdx.x] = total;
  __syncthreads();
  if (threadIdx.x < 32) {
    float4 acc = red[threadIdx.x];
#pragma unroll
    for (int gg = 1; gg < 16; ++gg) {
      float4 v = red[gg * 32 + threadIdx.x];
      acc.x += v.x; acc.y += v.y; acc.z += v.z; acc.w += v.w;
    }
    ((float4*)out)[(size_t)b * 32 + threadIdx.x] = acc;
  }
}

// ---- launch ------------------------------------------------------------

extern "C" void kernel_launch(void* const* d_in, const int* in_sizes, int n_in,
                              void* d_out, int out_size, void* d_ws, size_t ws_size,
                              hipStream_t stream) {
  const float* ea    = (const float*)d_in[0];
  const int*   batch = (const int*)d_in[1];
  const float* W1    = (const float*)d_in[2];
  const float* b1    = (const float*)d_in[3];
  const float* W2    = (const float*)d_in[4];
  const float* b2    = (const float*)d_in[5];
  float* out = (float*)d_out;

  // workspace layout (~12.1 MB)
  float*    exarr  = (float*)d_ws;                          // T*E f32
  unsigned* eid    = (unsigned*)(exarr + (size_t)T * E);    // T*E u32
  unsigned* cnt    = (unsigned*)(eid + (size_t)T * E);      // T*B u32
  unsigned* offs   = cnt + T * B;                           // T*B u32
  unsigned* cursor = offs + T * B;                          // T*B u32
  float*    ssum   = (float*)(cursor + T * B);              // T*B f32

  k_init<<<(T * B + 255) / 256, 256, 0, stream>>>(cnt, ssum);

  dim3 gs((E + 63) / 64, T);
  k_score<<<gs, 256, 0, stream>>>(ea, batch, W1, b1, W2, b2, exarr, ssum, cnt);
  k_scan<<<1, B, 0, stream>>>(cnt, offs, cursor);
  dim3 ge((E + 255) / 256, T);
  k_scatter<<<ge, 256, 0, stream>>>(batch, cursor, eid);
  k_pool<<<B, 512, 0, stream>>>(ea, exarr, ssum, offs, cnt, eid, out);
}